// Round 4
// baseline (263.191 us; speedup 1.0000x reference)
//
#include <hip/hip_runtime.h>

// DigitCapsules dynamic routing. Round-21 = Round-20 + k_iter psum-write FIX.
//  - R20 finally benched: absmax 0.215 (fail). Root cause: k_iter has 128
//    threads but must write NCLS*KDO=160 psum entries; classes 8,9 kept
//    k_uhat's stale partials. Fix: strided final write (tt += CHUNK).
//  - Everything else unchanged from the pass-elimination fusion:
//      * ut read TWICE total (was 5 reads in R17).
//      * s0 accumulated inside k_uhat (f32, pre-rounding) -> psum.
//      * k_iter = agreement + softmax + weighted partial-sum, w in f32.
//      * k_squash sums 9 chunk-partials, squashes, packs vph / writes out.
//  - Pipeline: pack_W, pack_x, k_uhat(+s0), squash, k_iter, squash, k_iter,
//    squash.  Predicted ~135-150 us (was 219).

#define NCLS   10
#define NCAPS  1152
#define KDO    16
#define CHUNK  128
#define NCH    9           // 1152 / 128
#define NB     256
#define BBAT   4           // batches per k_uhat block

typedef _Float16 h2_t __attribute__((ext_vector_type(2)));
typedef unsigned u4 __attribute__((ext_vector_type(4)));

static __device__ __forceinline__ unsigned pack2h(float a, float b) {
    union { _Float16 h[2]; unsigned u; } p;
    p.h[0] = (_Float16)a;
    p.h[1] = (_Float16)b;
    return p.u;
}

static __device__ __forceinline__ float dot8h(u4 r, const unsigned* xh) {
    union { unsigned u; h2_t h; } w0, w1, w2, w3, a0, a1, a2, a3;
    w0.u = r.x; w1.u = r.y; w2.u = r.z; w3.u = r.w;
    a0.u = xh[0]; a1.u = xh[1]; a2.u = xh[2]; a3.u = xh[3];
#if __has_builtin(__builtin_amdgcn_fdot2)
    float acc = __builtin_amdgcn_fdot2(w0.h, a0.h, 0.f, false);
    acc = __builtin_amdgcn_fdot2(w1.h, a1.h, acc, false);
    acc = __builtin_amdgcn_fdot2(w2.h, a2.h, acc, false);
    acc = __builtin_amdgcn_fdot2(w3.h, a3.h, acc, false);
    return acc;
#else
    return (float)w0.h.x * (float)a0.h.x + (float)w0.h.y * (float)a0.h.y
         + (float)w1.h.x * (float)a1.h.x + (float)w1.h.y * (float)a1.h.y
         + (float)w2.h.x * (float)a2.h.x + (float)w2.h.y * (float)a2.h.y
         + (float)w3.h.x * (float)a3.h.x + (float)w3.h.y * (float)a3.h.y;
#endif
}

static __device__ __forceinline__ float dot2h(unsigned a, unsigned b, float acc) {
    union { unsigned u; h2_t h; } pa, pb;
    pa.u = a; pb.u = b;
#if __has_builtin(__builtin_amdgcn_fdot2)
    return __builtin_amdgcn_fdot2(pa.h, pb.h, acc, false);
#else
    return acc + (float)pa.h.x * (float)pb.h.x + (float)pa.h.y * (float)pb.h.y;
#endif
}

static __device__ __forceinline__ float wave_sum(float v) {
    v += __shfl_xor(v, 32, 64);
    v += __shfl_xor(v, 16, 64);
    v += __shfl_xor(v,  8, 64);
    v += __shfl_xor(v,  4, 64);
    v += __shfl_xor(v,  2, 64);
    v += __shfl_xor(v,  1, 64);
    return v;
}

// Wt[c][d][i] : u4 holding f16 W[c,i,0,d,k] for k=0..7
__global__ __launch_bounds__(256)
void pack_W_f16(const float4* __restrict__ W4, u4* __restrict__ Wt) {
    int tid = blockIdx.x * blockDim.x + threadIdx.x;   // (c*NCAPS+i)*KDO + d
    if (tid >= NCLS * NCAPS * KDO) return;
    int d = tid & 15;
    int rest = tid >> 4;
    int i = rest % NCAPS;
    int c = rest / NCAPS;
    float4 a = W4[2 * tid];
    float4 b = W4[2 * tid + 1];
    u4 o;
    o.x = pack2h(a.x, a.y);
    o.y = pack2h(a.z, a.w);
    o.z = pack2h(b.x, b.y);
    o.w = pack2h(b.z, b.w);
    Wt[(size_t)(c * KDO + d) * NCAPS + i] = o;
}

// xp[b][i] : u4 of 8 f16 (the capsule's 8 inputs)
__global__ __launch_bounds__(256)
void pack_x_f16(const float4* __restrict__ x4, u4* __restrict__ xp) {
    int tid = blockIdx.x * blockDim.x + threadIdx.x;   // b*NCAPS + i
    if (tid >= NB * NCAPS) return;
    float4 a = x4[2 * tid];
    float4 b = x4[2 * tid + 1];
    u4 o;
    o.x = pack2h(a.x, a.y);
    o.y = pack2h(a.z, a.w);
    o.z = pack2h(b.x, b.y);
    o.w = pack2h(b.z, b.w);
    xp[tid] = o;
}

// ---- phase 1: ut + uniform-weight partial sums (s0).
// grid (NCH, NB/4, 5): 2 classes x 4 batches per block, 128 threads = 2 waves.
// psum layout: [b][ch][c][d] f32 (9 chunk-partials per (b,c,d)).
__global__ __launch_bounds__(CHUNK, 1)
void k_uhat(const u4* __restrict__ Wt, const u4* __restrict__ xp,
            u4* __restrict__ ut, float* __restrict__ psum)
{
    __shared__ float red0[2][2][BBAT][KDO];            // [wave][cc][k][d], 1 KB
    const int t    = threadIdx.x;
    const int lane = t & 63;
    const int wave = t >> 6;
    const int ii = blockIdx.x * CHUNK + t;
    const int b0 = blockIdx.y * BBAT;
    const int c0 = blockIdx.z * 2;

    u4 xq[BBAT];
    #pragma unroll
    for (int k = 0; k < BBAT; ++k)
        xq[k] = xp[(size_t)(b0 + k) * NCAPS + ii];

    #pragma unroll
    for (int cc = 0; cc < 2; ++cc) {
        const int c = c0 + cc;
        const u4* base = Wt + (size_t)c * KDO * NCAPS + ii;
        u4 r[KDO];                                 // 16 loads in flight
        #pragma unroll
        for (int d = 0; d < KDO; ++d)
            r[d] = __builtin_nontemporal_load(base + (size_t)d * NCAPS);

        #pragma unroll
        for (int k = 0; k < BBAT; ++k) {           // reuse W for 4 batches
            const unsigned* xh = (const unsigned*)&xq[k];
            u4 h0, h1;
            float sacc[KDO];                       // f32 u before f16 rounding
            #pragma unroll
            for (int dp = 0; dp < 8; ++dp) {
                float u0 = dot8h(r[2 * dp],     xh);
                float u1 = dot8h(r[2 * dp + 1], xh);
                sacc[2 * dp]     = u0;
                sacc[2 * dp + 1] = u1;
                unsigned pk = pack2h(u0, u1);
                if (dp < 4) ((unsigned*)&h0)[dp] = pk;
                else        ((unsigned*)&h1)[dp - 4] = pk;
            }
            u4* utb = ut + (size_t)(b0 + k) * NCLS * 2 * NCAPS;
            utb[((size_t)c * 2 + 0) * NCAPS + ii] = h0;
            utb[((size_t)c * 2 + 1) * NCAPS + ii] = h1;

            // wave-reduce the 16 dims over this wave's 64 capsules
            #pragma unroll
            for (int d = 0; d < KDO; ++d) sacc[d] = wave_sum(sacc[d]);
            float sel = 0.f;
            #pragma unroll
            for (int d = 0; d < KDO; ++d)
                sel = ((lane & 15) == d) ? sacc[d] : sel;
            if (lane < KDO) red0[wave][cc][k][lane] = sel;
        }
    }
    __syncthreads();
    {   // all 128 threads: combine the 2 waves, write chunk partial
        int cc = t >> 6, k = (t >> 4) & 3, d = t & 15;
        float v = red0[0][cc][k][d] + red0[1][cc][k][d];
        psum[(((size_t)(b0 + k) * NCH + blockIdx.x) * NCLS + (c0 + cc)) * KDO + d] = v;
    }
}

// ---- phase 2 (fused, x2): agreement + blog + softmax + weighted partial-sum.
// grid (NCH, NB), 128 threads; reads ut ONCE. w stays f32 (no wb roundtrip).
__global__ __launch_bounds__(CHUNK, 1)
void k_iter(const u4* __restrict__ ut, const unsigned* __restrict__ vph,
            float* __restrict__ blog, float* __restrict__ psum, int first)
{
    __shared__ unsigned vsh[NCLS * 8];
    __shared__ float red[2][NCLS * KDO];               // per-wave partials
    const int t    = threadIdx.x;
    const int lane = t & 63;
    const int wave = t >> 6;
    const int ii = blockIdx.x * CHUNK + t;
    const int b  = blockIdx.y;

    if (t < NCLS * 8) vsh[t] = vph[(size_t)b * NCLS * 8 + t];
    __syncthreads();

    const u4* utb = ut + (size_t)b * NCLS * 2 * NCAPS;
    float* blogb = blog + (size_t)b * NCLS * NCAPS;

    u4 up0[NCLS], up1[NCLS];                           // 80 VGPRs, static idx
    #pragma unroll
    for (int c = 0; c < NCLS; ++c) {
        up0[c] = utb[((size_t)c * 2 + 0) * NCAPS + ii];
        up1[c] = utb[((size_t)c * 2 + 1) * NCAPS + ii];
    }

    float bl[NCLS];
    #pragma unroll
    for (int c = 0; c < NCLS; ++c) {
        float a = first ? 0.f : blogb[(size_t)c * NCAPS + ii];
        #pragma unroll
        for (int dp = 0; dp < 4; ++dp)
            a = dot2h(((const unsigned*)&up0[c])[dp], vsh[c * 8 + dp], a);
        #pragma unroll
        for (int dp = 0; dp < 4; ++dp)
            a = dot2h(((const unsigned*)&up1[c])[dp], vsh[c * 8 + 4 + dp], a);
        bl[c] = a;
        if (first) blogb[(size_t)c * NCAPS + ii] = a;  // only it1's blog re-read
    }

    float m = bl[0];
    #pragma unroll
    for (int c = 1; c < NCLS; ++c) m = fmaxf(m, bl[c]);
    float den = 0.f;
    #pragma unroll
    for (int c = 0; c < NCLS; ++c) den += __expf(bl[c] - m);
    float sid = 1.f / den;
    #pragma unroll
    for (int c = 0; c < NCLS; ++c) bl[c] = __expf(bl[c] - m) * sid;  // bl := w

    // weighted sum: u fragments are already in registers
    #pragma unroll
    for (int c = 0; c < NCLS; ++c) {
        float sacc[KDO];
        #pragma unroll
        for (int dp = 0; dp < 8; ++dp) {
            union { unsigned u; h2_t h; } p;
            p.u = (dp < 4) ? ((const unsigned*)&up0[c])[dp]
                           : ((const unsigned*)&up1[c])[dp - 4];
            sacc[2 * dp]     = bl[c] * (float)p.h.x;
            sacc[2 * dp + 1] = bl[c] * (float)p.h.y;
        }
        #pragma unroll
        for (int d = 0; d < KDO; ++d) sacc[d] = wave_sum(sacc[d]);
        float sel = 0.f;
        #pragma unroll
        for (int d = 0; d < KDO; ++d)
            sel = ((lane & 15) == d) ? sacc[d] : sel;
        if (lane < KDO) red[wave][c * KDO + lane] = sel;
    }
    __syncthreads();
    // FIX (R21): 160 entries, 128 threads -> strided write. R20 left
    // t=128..159 (classes 8,9) stale => absmax 0.215 fail.
    for (int tt = t; tt < NCLS * KDO; tt += CHUNK)
        psum[((size_t)b * NCH + blockIdx.x) * (NCLS * KDO) + tt]
            = red[0][tt] + red[1][tt];
}

// ---- phase 3 (tiny, x3): sum 9 chunk-partials, squash, emit vph or out.
// grid (NB), 160 threads: t = c*16 + d.
__global__ __launch_bounds__(160)
void k_squash(const float* __restrict__ psum, float scale,
              unsigned* __restrict__ vph, float* __restrict__ out, int last)
{
    const int b = blockIdx.x;
    const int t = threadIdx.x;                         // 0..159
    if (t >= NCLS * KDO) return;
    const int lane = t & 63;

    float s = 0.f;
    #pragma unroll
    for (int ch = 0; ch < NCH; ++ch)
        s += psum[((size_t)b * NCH + ch) * (NCLS * KDO) + t];
    s *= scale;

    float nsq = s * s;                                 // reduce within c-group
    nsq += __shfl_xor(nsq, 8, 16);
    nsq += __shfl_xor(nsq, 4, 16);
    nsq += __shfl_xor(nsq, 2, 16);
    nsq += __shfl_xor(nsq, 1, 16);
    float sc = sqrtf(nsq) / (1.f + nsq);               // (nsq/(1+nsq))/sqrt(nsq)
    float vv = s * sc;

    if (last) {
        out[(size_t)b * NCLS * KDO + t] = vv;
    } else {
        float a  = __shfl(vv, (lane & 48) + 2 * (lane & 7), 64);
        float b2 = __shfl(vv, (lane & 48) + 2 * (lane & 7) + 1, 64);
        if ((lane & 15) < 8)
            vph[(size_t)(b * NCLS + (t >> 4)) * 8 + (t & 7)] = pack2h(a, b2);
    }
}

// ---- fallback (small ws): round-1 fp32 fused kernel, proven correct ----
__global__ __launch_bounds__(256, 2)
void caps_routing_fb(const float* __restrict__ x, const float* __restrict__ W,
                     float* __restrict__ out)
{
    const int b    = blockIdx.x;
    const int t    = threadIdx.x;
    const int lane = t & 63;
    const int wave = t >> 6;
    __shared__ float v_prev[NCLS * KDO];
    __shared__ float redf[NCLS * 4 * KDO];
    float4 xr[5][2];
    const float4* x4 = reinterpret_cast<const float4*>(x + (size_t)b * NCAPS * 8);
    #pragma unroll
    for (int j = 0; j < 5; ++j) {
        int i = t + 256 * j;
        if (i < NCAPS) { xr[j][0] = x4[2 * i]; xr[j][1] = x4[2 * i + 1]; }
    }
    float blog[5][NCLS];
    #pragma unroll
    for (int j = 0; j < 5; ++j)
        #pragma unroll
        for (int c = 0; c < NCLS; ++c) blog[j][c] = 0.f;
    const float4* W4 = reinterpret_cast<const float4*>(W);
    for (int it = 0; it < 3; ++it) {
        if (it > 0) {
            for (int c = 0; c < NCLS; ++c) {
                float vp[KDO];
                #pragma unroll
                for (int d = 0; d < KDO; ++d) vp[d] = v_prev[c * KDO + d];
                #pragma unroll
                for (int j = 0; j < 5; ++j) {
                    int i = t + 256 * j;
                    if (i < NCAPS) {
                        size_t wbx = (size_t)(c * NCAPS + i) * 32;
                        float a = 0.f;
                        #pragma unroll
                        for (int d = 0; d < KDO; ++d) {
                            float4 w0 = W4[wbx + 2 * d]; float4 w1 = W4[wbx + 2 * d + 1];
                            float u = w0.x*xr[j][0].x + w0.y*xr[j][0].y + w0.z*xr[j][0].z
                                    + w0.w*xr[j][0].w + w1.x*xr[j][1].x + w1.y*xr[j][1].y
                                    + w1.z*xr[j][1].z + w1.w*xr[j][1].w;
                            a += u * vp[d];
                        }
                        blog[j][c] += a;
                    }
                }
            }
        }
        float sm2[5], sid2[5];
        #pragma unroll
        for (int j = 0; j < 5; ++j) {
            int i = t + 256 * j;
            if (i < NCAPS) {
                float m = blog[j][0];
                #pragma unroll
                for (int c = 1; c < NCLS; ++c) m = fmaxf(m, blog[j][c]);
                float den = 0.f;
                #pragma unroll
                for (int c = 0; c < NCLS; ++c) den += __expf(blog[j][c] - m);
                sm2[j] = m; sid2[j] = 1.f / den;
            }
        }
        for (int c = 0; c < NCLS; ++c) {
            float acc[KDO];
            #pragma unroll
            for (int d = 0; d < KDO; ++d) acc[d] = 0.f;
            #pragma unroll
            for (int j = 0; j < 5; ++j) {
                int i = t + 256 * j;
                if (i < NCAPS) {
                    float wq = __expf(blog[j][c] - sm2[j]) * sid2[j];
                    size_t wbx = (size_t)(c * NCAPS + i) * 32;
                    #pragma unroll
                    for (int d = 0; d < KDO; ++d) {
                        float4 w0 = W4[wbx + 2 * d]; float4 w1 = W4[wbx + 2 * d + 1];
                        float u = w0.x*xr[j][0].x + w0.y*xr[j][0].y + w0.z*xr[j][0].z
                                + w0.w*xr[j][0].w + w1.x*xr[j][1].x + w1.y*xr[j][1].y
                                + w1.z*xr[j][1].z + w1.w*xr[j][1].w;
                        acc[d] += wq * u;
                    }
                }
            }
            #pragma unroll
            for (int d = 0; d < KDO; ++d) {
                float v = acc[d];
                v += __shfl_xor(v, 32, 64); v += __shfl_xor(v, 16, 64);
                v += __shfl_xor(v,  8, 64); v += __shfl_xor(v,  4, 64);
                v += __shfl_xor(v,  2, 64); v += __shfl_xor(v,  1, 64);
                if (lane == 0) redf[(c * 4 + wave) * KDO + d] = v;
            }
        }
        __syncthreads();
        if (t < NCLS * KDO) {
            int c = t >> 4, d = t & 15;
            float s = redf[(c*4+0)*KDO+d] + redf[(c*4+1)*KDO+d]
                    + redf[(c*4+2)*KDO+d] + redf[(c*4+3)*KDO+d];
            float nsq = s * s;
            nsq += __shfl_xor(nsq, 8, 16); nsq += __shfl_xor(nsq, 4, 16);
            nsq += __shfl_xor(nsq, 2, 16); nsq += __shfl_xor(nsq, 1, 16);
            float scale = sqrtf(nsq) / (1.f + nsq);
            float vv = s * scale;
            v_prev[t] = vv;
            if (it == 2) out[(size_t)b * NCLS * KDO + t] = vv;
        }
        __syncthreads();
    }
}

extern "C" void kernel_launch(void* const* d_in, const int* in_sizes, int n_in,
                              void* d_out, int out_size, void* d_ws, size_t ws_size,
                              hipStream_t stream) {
    const float* x = (const float*)d_in[0];              // [256, 1152, 8] fp32
    const float4* W4 = (const float4*)d_in[1];           // [10, 1152, 1, 16, 8] fp32
    float* out = (float*)d_out;                          // [256, 10, 1, 16] fp32
    (void)in_sizes; (void)n_in; (void)out_size;

    const size_t WT = (size_t)NCLS * KDO * NCAPS * sizeof(u4);            //  2.95 MB
    const size_t XH = (size_t)NB * NCAPS * sizeof(u4);                    //  4.72 MB
    const size_t UT = (size_t)NB * NCLS * 2 * NCAPS * sizeof(u4);         // 94.37 MB
    const size_t BL = (size_t)NB * NCLS * NCAPS * sizeof(float);          // 11.80 MB
    const size_t PS = (size_t)NB * NCH * NCLS * KDO * sizeof(float);      //  1.47 MB
    const size_t VP = (size_t)NB * NCLS * 8 * sizeof(unsigned);           //   80 KB
    const size_t need = WT + XH + UT + BL + PS + 2 * VP;                  // ~115 MB

    if (ws_size >= need) {
        char* p = (char*)d_ws;
        u4* Wt       = (u4*)p;       p += WT;
        u4* xp       = (u4*)p;       p += XH;
        u4* ut       = (u4*)p;       p += UT;
        float* blog  = (float*)p;    p += BL;
        float* ps    = (float*)p;    p += PS;
        unsigned* v0 = (unsigned*)p; p += VP;
        unsigned* v1 = (unsigned*)p;

        int totalW = NCLS * NCAPS * KDO;
        int totalX = NB * NCAPS;
        pack_W_f16<<<dim3((totalW + 255) / 256), dim3(256), 0, stream>>>(W4, Wt);
        pack_x_f16<<<dim3((totalX + 255) / 256), dim3(256), 0, stream>>>(
            (const float4*)x, xp);
        k_uhat<<<dim3(NCH, NB / BBAT, NCLS / 2), dim3(CHUNK), 0, stream>>>(
            Wt, xp, ut, ps);
        k_squash<<<dim3(NB), dim3(160), 0, stream>>>(ps, 0.1f, v0, out, 0);
        k_iter<<<dim3(NCH, NB), dim3(CHUNK), 0, stream>>>(ut, v0, blog, ps, 1);
        k_squash<<<dim3(NB), dim3(160), 0, stream>>>(ps, 1.0f, v1, out, 0);
        k_iter<<<dim3(NCH, NB), dim3(CHUNK), 0, stream>>>(ut, v1, blog, ps, 0);
        k_squash<<<dim3(NB), dim3(160), 0, stream>>>(ps, 1.0f, v0, out, 1);
    } else {
        caps_routing_fb<<<dim3(NB), dim3(256), 0, stream>>>(x, (const float*)d_in[1], out);
    }
}

// Round 5
// 159.956 us; speedup vs baseline: 1.6454x; 1.6454x over previous
//
#include <hip/hip_runtime.h>

// DigitCapsules dynamic routing. Round-22 = kill the shuffle storm.
//  - R21 passed but 263 us: k_iter=69.7 us. Cause: wave_sum per (c,d) =
//    6 shfl x 16 d x 10 c = 960 DS-ops/thread (k_uhat: 768). LDS-pipe
//    serialization dominates; VALUBusy 17.5%, HBM 9.9% (nothing else busy).
//  - FIX 1: butterfly multi-value reduce: 16 independent d-sums across a
//    wave in 17 shuffles (masks 32/16/8/4 halve the register set, send-the-
//    half-partner-needs; masks 2/1 finish). 5.6x fewer DS ops.
//    Lane l ends with S[d], d = bit4(l>>2) reversed: d = (l&4?1:0)|(l&8?2:0)
//    |(l&16?4:0)|(l&32?8:0); lanes sharing l>>2 agree.
//  - FIX 2: blog eliminated: blog2 = u.v0 + u.v1 = u.(v0+v1). k_squash#2
//    emits pack(v0+v1); k_iter#2 dots against it. -11.8 MB buffer, -20
//    wave-mem-instrs, no 'first' branch.
//  - Pipeline: pack_W, pack_x, k_uhat(+s0 partials), squash(v0), k_iter(v0),
//    squash(v0+v1), k_iter(v0+v1), squash(out). Predicted ~155-170 us.

#define NCLS   10
#define NCAPS  1152
#define KDO    16
#define CHUNK  128
#define NCH    9           // 1152 / 128
#define NB     256
#define BBAT   4           // batches per k_uhat block

typedef _Float16 h2_t __attribute__((ext_vector_type(2)));
typedef unsigned u4 __attribute__((ext_vector_type(4)));

static __device__ __forceinline__ unsigned pack2h(float a, float b) {
    union { _Float16 h[2]; unsigned u; } p;
    p.h[0] = (_Float16)a;
    p.h[1] = (_Float16)b;
    return p.u;
}

static __device__ __forceinline__ float dot8h(u4 r, const unsigned* xh) {
    union { unsigned u; h2_t h; } w0, w1, w2, w3, a0, a1, a2, a3;
    w0.u = r.x; w1.u = r.y; w2.u = r.z; w3.u = r.w;
    a0.u = xh[0]; a1.u = xh[1]; a2.u = xh[2]; a3.u = xh[3];
#if __has_builtin(__builtin_amdgcn_fdot2)
    float acc = __builtin_amdgcn_fdot2(w0.h, a0.h, 0.f, false);
    acc = __builtin_amdgcn_fdot2(w1.h, a1.h, acc, false);
    acc = __builtin_amdgcn_fdot2(w2.h, a2.h, acc, false);
    acc = __builtin_amdgcn_fdot2(w3.h, a3.h, acc, false);
    return acc;
#else
    return (float)w0.h.x * (float)a0.h.x + (float)w0.h.y * (float)a0.h.y
         + (float)w1.h.x * (float)a1.h.x + (float)w1.h.y * (float)a1.h.y
         + (float)w2.h.x * (float)a2.h.x + (float)w2.h.y * (float)a2.h.y
         + (float)w3.h.x * (float)a3.h.x + (float)w3.h.y * (float)a3.h.y;
#endif
}

static __device__ __forceinline__ float dot2h(unsigned a, unsigned b, float acc) {
    union { unsigned u; h2_t h; } pa, pb;
    pa.u = a; pb.u = b;
#if __has_builtin(__builtin_amdgcn_fdot2)
    return __builtin_amdgcn_fdot2(pa.h, pb.h, acc, false);
#else
    return acc + (float)pa.h.x * (float)pb.h.x + (float)pa.h.y * (float)pb.h.y;
#endif
}

// Butterfly reduce of 16 per-lane values across a 64-lane wave: 17 shuffles.
// Returns (per lane) S[d(lane)], d = (l&4?1:0)|(l&8?2:0)|(l&16?4:0)|(l&32?8:0).
// All 4 lanes sharing (l>>2) hold the same result.
static __device__ __forceinline__ float bfly16(const float v[KDO], int lane) {
    float a[8];
    #pragma unroll
    for (int i = 0; i < 8; ++i) {
        float send = (lane & 32) ? v[i] : v[i + 8];
        float recv = __shfl_xor(send, 32, 64);
        float keep = (lane & 32) ? v[i + 8] : v[i];
        a[i] = keep + recv;
    }
    float b[4];
    #pragma unroll
    for (int i = 0; i < 4; ++i) {
        float send = (lane & 16) ? a[i] : a[i + 4];
        float recv = __shfl_xor(send, 16, 64);
        float keep = (lane & 16) ? a[i + 4] : a[i];
        b[i] = keep + recv;
    }
    float c[2];
    #pragma unroll
    for (int i = 0; i < 2; ++i) {
        float send = (lane & 8) ? b[i] : b[i + 2];
        float recv = __shfl_xor(send, 8, 64);
        float keep = (lane & 8) ? b[i + 2] : b[i];
        c[i] = keep + recv;
    }
    float e;
    {
        float send = (lane & 4) ? c[0] : c[1];
        float recv = __shfl_xor(send, 4, 64);
        float keep = (lane & 4) ? c[1] : c[0];
        e = keep + recv;
    }
    e += __shfl_xor(e, 2, 64);
    e += __shfl_xor(e, 1, 64);
    return e;
}

static __device__ __forceinline__ int bfly_d(int lane) {
    return ((lane & 4) ? 1 : 0) | ((lane & 8) ? 2 : 0)
         | ((lane & 16) ? 4 : 0) | ((lane & 32) ? 8 : 0);
}

// Wt[c][d][i] : u4 holding f16 W[c,i,0,d,k] for k=0..7
__global__ __launch_bounds__(256)
void pack_W_f16(const float4* __restrict__ W4, u4* __restrict__ Wt) {
    int tid = blockIdx.x * blockDim.x + threadIdx.x;   // (c*NCAPS+i)*KDO + d
    if (tid >= NCLS * NCAPS * KDO) return;
    int d = tid & 15;
    int rest = tid >> 4;
    int i = rest % NCAPS;
    int c = rest / NCAPS;
    float4 a = W4[2 * tid];
    float4 b = W4[2 * tid + 1];
    u4 o;
    o.x = pack2h(a.x, a.y);
    o.y = pack2h(a.z, a.w);
    o.z = pack2h(b.x, b.y);
    o.w = pack2h(b.z, b.w);
    Wt[(size_t)(c * KDO + d) * NCAPS + i] = o;
}

// xp[b][i] : u4 of 8 f16 (the capsule's 8 inputs)
__global__ __launch_bounds__(256)
void pack_x_f16(const float4* __restrict__ x4, u4* __restrict__ xp) {
    int tid = blockIdx.x * blockDim.x + threadIdx.x;   // b*NCAPS + i
    if (tid >= NB * NCAPS) return;
    float4 a = x4[2 * tid];
    float4 b = x4[2 * tid + 1];
    u4 o;
    o.x = pack2h(a.x, a.y);
    o.y = pack2h(a.z, a.w);
    o.z = pack2h(b.x, b.y);
    o.w = pack2h(b.z, b.w);
    xp[tid] = o;
}

// ---- phase 1: ut + uniform-weight partial sums (s0).
// grid (NCH, NB/4, 5): 2 classes x 4 batches per block, 128 threads = 2 waves.
// psum layout: [b][ch][c][d] f32 (9 chunk-partials per (b,c,d)).
__global__ __launch_bounds__(CHUNK, 1)
void k_uhat(const u4* __restrict__ Wt, const u4* __restrict__ xp,
            u4* __restrict__ ut, float* __restrict__ psum)
{
    __shared__ float red0[2][2][BBAT][KDO];            // [wave][cc][k][d], 1 KB
    const int t    = threadIdx.x;
    const int lane = t & 63;
    const int wave = t >> 6;
    const int ii = blockIdx.x * CHUNK + t;
    const int b0 = blockIdx.y * BBAT;
    const int c0 = blockIdx.z * 2;
    const int dm = bfly_d(lane);

    u4 xq[BBAT];
    #pragma unroll
    for (int k = 0; k < BBAT; ++k)
        xq[k] = xp[(size_t)(b0 + k) * NCAPS + ii];

    #pragma unroll
    for (int cc = 0; cc < 2; ++cc) {
        const int c = c0 + cc;
        const u4* base = Wt + (size_t)c * KDO * NCAPS + ii;
        u4 r[KDO];                                 // 16 loads in flight
        #pragma unroll
        for (int d = 0; d < KDO; ++d)
            r[d] = __builtin_nontemporal_load(base + (size_t)d * NCAPS);

        #pragma unroll
        for (int k = 0; k < BBAT; ++k) {           // reuse W for 4 batches
            const unsigned* xh = (const unsigned*)&xq[k];
            u4 h0, h1;
            float sacc[KDO];                       // f32 u before f16 rounding
            #pragma unroll
            for (int dp = 0; dp < 8; ++dp) {
                float u0 = dot8h(r[2 * dp],     xh);
                float u1 = dot8h(r[2 * dp + 1], xh);
                sacc[2 * dp]     = u0;
                sacc[2 * dp + 1] = u1;
                unsigned pk = pack2h(u0, u1);
                if (dp < 4) ((unsigned*)&h0)[dp] = pk;
                else        ((unsigned*)&h1)[dp - 4] = pk;
            }
            u4* utb = ut + (size_t)(b0 + k) * NCLS * 2 * NCAPS;
            utb[((size_t)c * 2 + 0) * NCAPS + ii] = h0;
            utb[((size_t)c * 2 + 1) * NCAPS + ii] = h1;

            // butterfly: 17 shuffles for all 16 d-sums (was 96)
            float e = bfly16(sacc, lane);
            if ((lane & 3) == 0) red0[wave][cc][k][dm] = e;
        }
    }
    __syncthreads();
    {   // all 128 threads: combine the 2 waves, write chunk partial
        int cc = t >> 6, k = (t >> 4) & 3, d = t & 15;
        float v = red0[0][cc][k][d] + red0[1][cc][k][d];
        psum[(((size_t)(b0 + k) * NCH + blockIdx.x) * NCLS + (c0 + cc)) * KDO + d] = v;
    }
}

// ---- phase 2 (fused, x2): agreement + softmax + weighted partial-sum.
// grid (NCH, NB), 128 threads; reads ut ONCE. No blog: iter2's logits are
// u.(v0+v1), supplied pre-summed in vph.
__global__ __launch_bounds__(CHUNK, 1)
void k_iter(const u4* __restrict__ ut, const unsigned* __restrict__ vph,
            float* __restrict__ psum)
{
    __shared__ unsigned vsh[NCLS * 8];
    __shared__ float red[2][NCLS * KDO];               // per-wave partials
    const int t    = threadIdx.x;
    const int lane = t & 63;
    const int wave = t >> 6;
    const int ii = blockIdx.x * CHUNK + t;
    const int b  = blockIdx.y;
    const int dm = bfly_d(lane);

    if (t < NCLS * 8) vsh[t] = vph[(size_t)b * NCLS * 8 + t];
    __syncthreads();

    const u4* utb = ut + (size_t)b * NCLS * 2 * NCAPS;

    u4 up0[NCLS], up1[NCLS];                           // 80 VGPRs, static idx
    #pragma unroll
    for (int c = 0; c < NCLS; ++c) {
        up0[c] = utb[((size_t)c * 2 + 0) * NCAPS + ii];
        up1[c] = utb[((size_t)c * 2 + 1) * NCAPS + ii];
    }

    float bl[NCLS];
    #pragma unroll
    for (int c = 0; c < NCLS; ++c) {
        float a = 0.f;
        #pragma unroll
        for (int dp = 0; dp < 4; ++dp)
            a = dot2h(((const unsigned*)&up0[c])[dp], vsh[c * 8 + dp], a);
        #pragma unroll
        for (int dp = 0; dp < 4; ++dp)
            a = dot2h(((const unsigned*)&up1[c])[dp], vsh[c * 8 + 4 + dp], a);
        bl[c] = a;
    }

    float m = bl[0];
    #pragma unroll
    for (int c = 1; c < NCLS; ++c) m = fmaxf(m, bl[c]);
    float den = 0.f;
    #pragma unroll
    for (int c = 0; c < NCLS; ++c) den += __expf(bl[c] - m);
    float sid = 1.f / den;
    #pragma unroll
    for (int c = 0; c < NCLS; ++c) bl[c] = __expf(bl[c] - m) * sid;  // bl := w

    // weighted sum; butterfly reduce (17 shuffles/class, was 96)
    #pragma unroll
    for (int c = 0; c < NCLS; ++c) {
        float sacc[KDO];
        #pragma unroll
        for (int dp = 0; dp < 8; ++dp) {
            union { unsigned u; h2_t h; } p;
            p.u = (dp < 4) ? ((const unsigned*)&up0[c])[dp]
                           : ((const unsigned*)&up1[c])[dp - 4];
            sacc[2 * dp]     = bl[c] * (float)p.h.x;
            sacc[2 * dp + 1] = bl[c] * (float)p.h.y;
        }
        float e = bfly16(sacc, lane);
        if ((lane & 3) == 0) red[wave][c * KDO + dm] = e;
    }
    __syncthreads();
    // 160 entries, 128 threads -> strided write (R21 fix kept).
    for (int tt = t; tt < NCLS * KDO; tt += CHUNK)
        psum[((size_t)b * NCH + blockIdx.x) * (NCLS * KDO) + tt]
            = red[0][tt] + red[1][tt];
}

// ---- phase 3 (tiny, x3): sum 9 chunk-partials, squash, emit vph or out.
// grid (NB), 160 threads: t = c*16 + d. If vprev != null, vph gets
// pack(v_prev + v) (for the blog2 = u.(v0+v1) identity).
__global__ __launch_bounds__(160)
void k_squash(const float* __restrict__ psum, float scale,
              const unsigned* __restrict__ vprev,
              unsigned* __restrict__ vph, float* __restrict__ out, int last)
{
    const int b = blockIdx.x;
    const int t = threadIdx.x;                         // 0..159
    if (t >= NCLS * KDO) return;
    const int lane = t & 63;

    float s = 0.f;
    #pragma unroll
    for (int ch = 0; ch < NCH; ++ch)
        s += psum[((size_t)b * NCH + ch) * (NCLS * KDO) + t];
    s *= scale;

    float nsq = s * s;                                 // reduce within c-group
    nsq += __shfl_xor(nsq, 8, 16);
    nsq += __shfl_xor(nsq, 4, 16);
    nsq += __shfl_xor(nsq, 2, 16);
    nsq += __shfl_xor(nsq, 1, 16);
    float sc = sqrtf(nsq) / (1.f + nsq);               // (nsq/(1+nsq))/sqrt(nsq)
    float vv = s * sc;

    if (last) {
        out[(size_t)b * NCLS * KDO + t] = vv;
    } else {
        if (vprev) {                                   // vv += v_prev[c][d]
            unsigned pw = vprev[(size_t)(b * NCLS + (t >> 4)) * 8 + ((t & 15) >> 1)];
            union { unsigned u; h2_t h; } pv; pv.u = pw;
            vv += (float)((t & 1) ? pv.h.y : pv.h.x);
        }
        float a  = __shfl(vv, (lane & 48) + 2 * (lane & 7), 64);
        float b2 = __shfl(vv, (lane & 48) + 2 * (lane & 7) + 1, 64);
        if ((lane & 15) < 8)
            vph[(size_t)(b * NCLS + (t >> 4)) * 8 + (t & 7)] = pack2h(a, b2);
    }
}

// ---- fallback (small ws): round-1 fp32 fused kernel, proven correct ----
__global__ __launch_bounds__(256, 2)
void caps_routing_fb(const float* __restrict__ x, const float* __restrict__ W,
                     float* __restrict__ out)
{
    const int b    = blockIdx.x;
    const int t    = threadIdx.x;
    const int lane = t & 63;
    const int wave = t >> 6;
    __shared__ float v_prev[NCLS * KDO];
    __shared__ float redf[NCLS * 4 * KDO];
    float4 xr[5][2];
    const float4* x4 = reinterpret_cast<const float4*>(x + (size_t)b * NCAPS * 8);
    #pragma unroll
    for (int j = 0; j < 5; ++j) {
        int i = t + 256 * j;
        if (i < NCAPS) { xr[j][0] = x4[2 * i]; xr[j][1] = x4[2 * i + 1]; }
    }
    float blog[5][NCLS];
    #pragma unroll
    for (int j = 0; j < 5; ++j)
        #pragma unroll
        for (int c = 0; c < NCLS; ++c) blog[j][c] = 0.f;
    const float4* W4 = reinterpret_cast<const float4*>(W);
    for (int it = 0; it < 3; ++it) {
        if (it > 0) {
            for (int c = 0; c < NCLS; ++c) {
                float vp[KDO];
                #pragma unroll
                for (int d = 0; d < KDO; ++d) vp[d] = v_prev[c * KDO + d];
                #pragma unroll
                for (int j = 0; j < 5; ++j) {
                    int i = t + 256 * j;
                    if (i < NCAPS) {
                        size_t wbx = (size_t)(c * NCAPS + i) * 32;
                        float a = 0.f;
                        #pragma unroll
                        for (int d = 0; d < KDO; ++d) {
                            float4 w0 = W4[wbx + 2 * d]; float4 w1 = W4[wbx + 2 * d + 1];
                            float u = w0.x*xr[j][0].x + w0.y*xr[j][0].y + w0.z*xr[j][0].z
                                    + w0.w*xr[j][0].w + w1.x*xr[j][1].x + w1.y*xr[j][1].y
                                    + w1.z*xr[j][1].z + w1.w*xr[j][1].w;
                            a += u * vp[d];
                        }
                        blog[j][c] += a;
                    }
                }
            }
        }
        float sm2[5], sid2[5];
        #pragma unroll
        for (int j = 0; j < 5; ++j) {
            int i = t + 256 * j;
            if (i < NCAPS) {
                float m = blog[j][0];
                #pragma unroll
                for (int c = 1; c < NCLS; ++c) m = fmaxf(m, blog[j][c]);
                float den = 0.f;
                #pragma unroll
                for (int c = 0; c < NCLS; ++c) den += __expf(blog[j][c] - m);
                sm2[j] = m; sid2[j] = 1.f / den;
            }
        }
        for (int c = 0; c < NCLS; ++c) {
            float acc[KDO];
            #pragma unroll
            for (int d = 0; d < KDO; ++d) acc[d] = 0.f;
            #pragma unroll
            for (int j = 0; j < 5; ++j) {
                int i = t + 256 * j;
                if (i < NCAPS) {
                    float wq = __expf(blog[j][c] - sm2[j]) * sid2[j];
                    size_t wbx = (size_t)(c * NCAPS + i) * 32;
                    #pragma unroll
                    for (int d = 0; d < KDO; ++d) {
                        float4 w0 = W4[wbx + 2 * d]; float4 w1 = W4[wbx + 2 * d + 1];
                        float u = w0.x*xr[j][0].x + w0.y*xr[j][0].y + w0.z*xr[j][0].z
                                + w0.w*xr[j][0].w + w1.x*xr[j][1].x + w1.y*xr[j][1].y
                                + w1.z*xr[j][1].z + w1.w*xr[j][1].w;
                        acc[d] += wq * u;
                    }
                }
            }
            #pragma unroll
            for (int d = 0; d < KDO; ++d) {
                float v = acc[d];
                v += __shfl_xor(v, 32, 64); v += __shfl_xor(v, 16, 64);
                v += __shfl_xor(v,  8, 64); v += __shfl_xor(v,  4, 64);
                v += __shfl_xor(v,  2, 64); v += __shfl_xor(v,  1, 64);
                if (lane == 0) redf[(c * 4 + wave) * KDO + d] = v;
            }
        }
        __syncthreads();
        if (t < NCLS * KDO) {
            int c = t >> 4, d = t & 15;
            float s = redf[(c*4+0)*KDO+d] + redf[(c*4+1)*KDO+d]
                    + redf[(c*4+2)*KDO+d] + redf[(c*4+3)*KDO+d];
            float nsq = s * s;
            nsq += __shfl_xor(nsq, 8, 16); nsq += __shfl_xor(nsq, 4, 16);
            nsq += __shfl_xor(nsq, 2, 16); nsq += __shfl_xor(nsq, 1, 16);
            float scale = sqrtf(nsq) / (1.f + nsq);
            float vv = s * scale;
            v_prev[t] = vv;
            if (it == 2) out[(size_t)b * NCLS * KDO + t] = vv;
        }
        __syncthreads();
    }
}

extern "C" void kernel_launch(void* const* d_in, const int* in_sizes, int n_in,
                              void* d_out, int out_size, void* d_ws, size_t ws_size,
                              hipStream_t stream) {
    const float* x = (const float*)d_in[0];              // [256, 1152, 8] fp32
    const float4* W4 = (const float4*)d_in[1];           // [10, 1152, 1, 16, 8] fp32
    float* out = (float*)d_out;                          // [256, 10, 1, 16] fp32
    (void)in_sizes; (void)n_in; (void)out_size;

    const size_t WT = (size_t)NCLS * KDO * NCAPS * sizeof(u4);            //  2.95 MB
    const size_t XH = (size_t)NB * NCAPS * sizeof(u4);                    //  4.72 MB
    const size_t UT = (size_t)NB * NCLS * 2 * NCAPS * sizeof(u4);         // 94.37 MB
    const size_t PS = (size_t)NB * NCH * NCLS * KDO * sizeof(float);      //  1.47 MB
    const size_t VP = (size_t)NB * NCLS * 8 * sizeof(unsigned);           //   80 KB
    const size_t need = WT + XH + UT + PS + 2 * VP;                       // ~104 MB

    if (ws_size >= need) {
        char* p = (char*)d_ws;
        u4* Wt       = (u4*)p;       p += WT;
        u4* xp       = (u4*)p;       p += XH;
        u4* ut       = (u4*)p;       p += UT;
        float* ps    = (float*)p;    p += PS;
        unsigned* v0 = (unsigned*)p; p += VP;
        unsigned* vs = (unsigned*)p;                     // pack(v0+v1)

        int totalW = NCLS * NCAPS * KDO;
        int totalX = NB * NCAPS;
        pack_W_f16<<<dim3((totalW + 255) / 256), dim3(256), 0, stream>>>(W4, Wt);
        pack_x_f16<<<dim3((totalX + 255) / 256), dim3(256), 0, stream>>>(
            (const float4*)x, xp);
        k_uhat<<<dim3(NCH, NB / BBAT, NCLS / 2), dim3(CHUNK), 0, stream>>>(
            Wt, xp, ut, ps);
        k_squash<<<dim3(NB), dim3(160), 0, stream>>>(ps, 0.1f, nullptr, v0, out, 0);
        k_iter<<<dim3(NCH, NB), dim3(CHUNK), 0, stream>>>(ut, v0, ps);
        k_squash<<<dim3(NB), dim3(160), 0, stream>>>(ps, 1.0f, v0, vs, out, 0);
        k_iter<<<dim3(NCH, NB), dim3(CHUNK), 0, stream>>>(ut, vs, ps);
        k_squash<<<dim3(NB), dim3(160), 0, stream>>>(ps, 1.0f, nullptr, nullptr, out, 1);
    } else {
        caps_routing_fb<<<dim3(NB), dim3(256), 0, stream>>>(x, (const float*)d_in[1], out);
    }
}

// Round 6
// 135.215 us; speedup vs baseline: 1.9465x; 1.1830x over previous
//
#include <hip/hip_runtime.h>

// DigitCapsules dynamic routing. Round-23.
//  - R22: 160 us. k_uhat now dominant (57 us): FETCH 32 MB = 10x Wt size
//    (nontemporal evicts W), 53 wave-mem-instrs/thread at ~73cyc law.
//  - FIX 1: k_uhat BBAT 4->8 (one W load-set feeds 8 batches; mem-instrs
//    per ut byte -30%) + drop nontemporal on Wt (stays L2-resident).
//  - FIX 2: k_iter computes v IN-BLOCK from psum (1.5 MB, ~9-18 scalar
//    loads/thread + small LDS): deletes k_squash#1/#2, vph, 2 launch gaps.
//    ps0 (k_uhat Su partials), ps1 (iter1 s1), ps2 (iter2 s2) - no races.
//    iter1: logits = u.v0, v0 = squash(0.1*ps0). iter2: logits = u.(v0+v1).
//  - Pipeline (6 launches): pack_W, pack_x, k_uhat, k_iter, k_iter,
//    k_squash(out). Predicted ~130-140 us.

#define NCLS   10
#define NCAPS  1152
#define KDO    16
#define CHUNK  128
#define NCH    9           // 1152 / 128
#define NB     256
#define BBAT   8           // batches per k_uhat block

typedef _Float16 h2_t __attribute__((ext_vector_type(2)));
typedef unsigned u4 __attribute__((ext_vector_type(4)));

static __device__ __forceinline__ unsigned pack2h(float a, float b) {
    union { _Float16 h[2]; unsigned u; } p;
    p.h[0] = (_Float16)a;
    p.h[1] = (_Float16)b;
    return p.u;
}

static __device__ __forceinline__ float dot8h(u4 r, const unsigned* xh) {
    union { unsigned u; h2_t h; } w0, w1, w2, w3, a0, a1, a2, a3;
    w0.u = r.x; w1.u = r.y; w2.u = r.z; w3.u = r.w;
    a0.u = xh[0]; a1.u = xh[1]; a2.u = xh[2]; a3.u = xh[3];
#if __has_builtin(__builtin_amdgcn_fdot2)
    float acc = __builtin_amdgcn_fdot2(w0.h, a0.h, 0.f, false);
    acc = __builtin_amdgcn_fdot2(w1.h, a1.h, acc, false);
    acc = __builtin_amdgcn_fdot2(w2.h, a2.h, acc, false);
    acc = __builtin_amdgcn_fdot2(w3.h, a3.h, acc, false);
    return acc;
#else
    return (float)w0.h.x * (float)a0.h.x + (float)w0.h.y * (float)a0.h.y
         + (float)w1.h.x * (float)a1.h.x + (float)w1.h.y * (float)a1.h.y
         + (float)w2.h.x * (float)a2.h.x + (float)w2.h.y * (float)a2.h.y
         + (float)w3.h.x * (float)a3.h.x + (float)w3.h.y * (float)a3.h.y;
#endif
}

static __device__ __forceinline__ float dot2h(unsigned a, unsigned b, float acc) {
    union { unsigned u; h2_t h; } pa, pb;
    pa.u = a; pb.u = b;
#if __has_builtin(__builtin_amdgcn_fdot2)
    return __builtin_amdgcn_fdot2(pa.h, pb.h, acc, false);
#else
    return acc + (float)pa.h.x * (float)pb.h.x + (float)pa.h.y * (float)pb.h.y;
#endif
}

// Butterfly reduce of 16 per-lane values across a 64-lane wave: 17 shuffles.
// Returns (per lane) S[d(lane)], d = (l&4?1:0)|(l&8?2:0)|(l&16?4:0)|(l&32?8:0).
// All 4 lanes sharing (l>>2) hold the same result.
static __device__ __forceinline__ float bfly16(const float v[KDO], int lane) {
    float a[8];
    #pragma unroll
    for (int i = 0; i < 8; ++i) {
        float send = (lane & 32) ? v[i] : v[i + 8];
        float recv = __shfl_xor(send, 32, 64);
        float keep = (lane & 32) ? v[i + 8] : v[i];
        a[i] = keep + recv;
    }
    float b[4];
    #pragma unroll
    for (int i = 0; i < 4; ++i) {
        float send = (lane & 16) ? a[i] : a[i + 4];
        float recv = __shfl_xor(send, 16, 64);
        float keep = (lane & 16) ? a[i + 4] : a[i];
        b[i] = keep + recv;
    }
    float c[2];
    #pragma unroll
    for (int i = 0; i < 2; ++i) {
        float send = (lane & 8) ? b[i] : b[i + 2];
        float recv = __shfl_xor(send, 8, 64);
        float keep = (lane & 8) ? b[i + 2] : b[i];
        c[i] = keep + recv;
    }
    float e;
    {
        float send = (lane & 4) ? c[0] : c[1];
        float recv = __shfl_xor(send, 4, 64);
        float keep = (lane & 4) ? c[1] : c[0];
        e = keep + recv;
    }
    e += __shfl_xor(e, 2, 64);
    e += __shfl_xor(e, 1, 64);
    return e;
}

static __device__ __forceinline__ int bfly_d(int lane) {
    return ((lane & 4) ? 1 : 0) | ((lane & 8) ? 2 : 0)
         | ((lane & 16) ? 4 : 0) | ((lane & 32) ? 8 : 0);
}

// Wt[c][d][i] : u4 holding f16 W[c,i,0,d,k] for k=0..7
__global__ __launch_bounds__(256)
void pack_W_f16(const float4* __restrict__ W4, u4* __restrict__ Wt) {
    int tid = blockIdx.x * blockDim.x + threadIdx.x;   // (c*NCAPS+i)*KDO + d
    if (tid >= NCLS * NCAPS * KDO) return;
    int d = tid & 15;
    int rest = tid >> 4;
    int i = rest % NCAPS;
    int c = rest / NCAPS;
    float4 a = W4[2 * tid];
    float4 b = W4[2 * tid + 1];
    u4 o;
    o.x = pack2h(a.x, a.y);
    o.y = pack2h(a.z, a.w);
    o.z = pack2h(b.x, b.y);
    o.w = pack2h(b.z, b.w);
    Wt[(size_t)(c * KDO + d) * NCAPS + i] = o;
}

// xp[b][i] : u4 of 8 f16 (the capsule's 8 inputs)
__global__ __launch_bounds__(256)
void pack_x_f16(const float4* __restrict__ x4, u4* __restrict__ xp) {
    int tid = blockIdx.x * blockDim.x + threadIdx.x;   // b*NCAPS + i
    if (tid >= NB * NCAPS) return;
    float4 a = x4[2 * tid];
    float4 b = x4[2 * tid + 1];
    u4 o;
    o.x = pack2h(a.x, a.y);
    o.y = pack2h(a.z, a.w);
    o.z = pack2h(b.x, b.y);
    o.w = pack2h(b.z, b.w);
    xp[tid] = o;
}

// ---- phase 1: ut + uniform-weight partial sums (s0).
// grid (NCH, NB/8, 5): 2 classes x 8 batches per block, 128 threads = 2 waves.
// psum layout: [b][ch][c][d] f32 (9 chunk-partials per (b,c,d)).
__global__ __launch_bounds__(CHUNK, 1)
void k_uhat(const u4* __restrict__ Wt, const u4* __restrict__ xp,
            u4* __restrict__ ut, float* __restrict__ psum)
{
    __shared__ float red0[2][2][BBAT][KDO];            // [wave][cc][k][d], 2 KB
    const int t    = threadIdx.x;
    const int lane = t & 63;
    const int wave = t >> 6;
    const int ii = blockIdx.x * CHUNK + t;
    const int b0 = blockIdx.y * BBAT;
    const int c0 = blockIdx.z * 2;
    const int dm = bfly_d(lane);

    u4 xq[BBAT];
    #pragma unroll
    for (int k = 0; k < BBAT; ++k)
        xq[k] = xp[(size_t)(b0 + k) * NCAPS + ii];

    #pragma unroll
    for (int cc = 0; cc < 2; ++cc) {
        const int c = c0 + cc;
        const u4* base = Wt + (size_t)c * KDO * NCAPS + ii;
        u4 r[KDO];                                 // 16 loads in flight
        #pragma unroll
        for (int d = 0; d < KDO; ++d)
            r[d] = base[(size_t)d * NCAPS];        // regular load: keep W in L2

        #pragma unroll
        for (int k = 0; k < BBAT; ++k) {           // reuse W for 8 batches
            const unsigned* xh = (const unsigned*)&xq[k];
            u4 h0, h1;
            float sacc[KDO];                       // f32 u before f16 rounding
            #pragma unroll
            for (int dp = 0; dp < 8; ++dp) {
                float u0 = dot8h(r[2 * dp],     xh);
                float u1 = dot8h(r[2 * dp + 1], xh);
                sacc[2 * dp]     = u0;
                sacc[2 * dp + 1] = u1;
                unsigned pk = pack2h(u0, u1);
                if (dp < 4) ((unsigned*)&h0)[dp] = pk;
                else        ((unsigned*)&h1)[dp - 4] = pk;
            }
            u4* utb = ut + (size_t)(b0 + k) * NCLS * 2 * NCAPS;
            utb[((size_t)c * 2 + 0) * NCAPS + ii] = h0;
            utb[((size_t)c * 2 + 1) * NCAPS + ii] = h1;

            // butterfly: 17 shuffles for all 16 d-sums
            float e = bfly16(sacc, lane);
            if ((lane & 3) == 0) red0[wave][cc][k][dm] = e;
        }
    }
    __syncthreads();
    // 2cc x 8k x 16d = 256 entries, 128 threads -> strided x2
    for (int tt = t; tt < 2 * BBAT * KDO; tt += CHUNK) {
        int cc = tt >> 7, k = (tt >> 4) & 7, d = tt & 15;
        float v = red0[0][cc][k][d] + red0[1][cc][k][d];
        psum[(((size_t)(b0 + k) * NCH + blockIdx.x) * NCLS + (c0 + cc)) * KDO + d] = v;
    }
}

// ---- phase 2 (fused, x2): in-block v from psum + agreement + softmax +
// weighted partial-sum. grid (NCH, NB), 128 threads; reads ut ONCE.
// v_logit = squash(scaleA*sum(psA)) [+ squash(sum(psB)) if psB].
__global__ __launch_bounds__(CHUNK, 1)
void k_iter(const u4* __restrict__ ut,
            const float* __restrict__ psA, float scaleA,
            const float* __restrict__ psB,
            float* __restrict__ psOut)
{
    __shared__ float s0sh[NCLS * KDO];
    __shared__ float s1sh[NCLS * KDO];
    __shared__ float scsh[2][NCLS];
    __shared__ unsigned vsh[NCLS * 8];
    __shared__ float red[2][NCLS * KDO];               // per-wave partials
    const int t    = threadIdx.x;
    const int lane = t & 63;
    const int wave = t >> 6;
    const int ii = blockIdx.x * CHUNK + t;
    const int b  = blockIdx.y;
    const int dm = bfly_d(lane);

    // ---- in-block squash: s = sum of 9 chunk partials ----
    for (int tt = t; tt < NCLS * KDO; tt += CHUNK) {
        float s = 0.f;
        #pragma unroll
        for (int ch = 0; ch < NCH; ++ch)
            s += psA[((size_t)b * NCH + ch) * (NCLS * KDO) + tt];
        s0sh[tt] = s * scaleA;
        if (psB) {
            float s2 = 0.f;
            #pragma unroll
            for (int ch = 0; ch < NCH; ++ch)
                s2 += psB[((size_t)b * NCH + ch) * (NCLS * KDO) + tt];
            s1sh[tt] = s2;
        }
    }
    __syncthreads();
    if (t < (psB ? 2 * NCLS : NCLS)) {
        int which = t >= NCLS;
        int c = which ? t - NCLS : t;
        const float* ss = which ? s1sh : s0sh;
        float nsq = 0.f;
        #pragma unroll
        for (int d = 0; d < KDO; ++d) {
            float x = ss[c * KDO + d];
            nsq += x * x;
        }
        scsh[which][c] = sqrtf(nsq) / (1.f + nsq);
    }
    __syncthreads();
    if (t < NCLS * 8) {
        int c = t >> 3, dp = t & 7;
        float va = s0sh[c * KDO + 2 * dp]     * scsh[0][c];
        float vb = s0sh[c * KDO + 2 * dp + 1] * scsh[0][c];
        if (psB) {
            va += s1sh[c * KDO + 2 * dp]     * scsh[1][c];
            vb += s1sh[c * KDO + 2 * dp + 1] * scsh[1][c];
        }
        vsh[t] = pack2h(va, vb);
    }
    __syncthreads();

    // ---- agreement + softmax + weighted sum ----
    const u4* utb = ut + (size_t)b * NCLS * 2 * NCAPS;

    u4 up0[NCLS], up1[NCLS];
    #pragma unroll
    for (int c = 0; c < NCLS; ++c) {
        up0[c] = utb[((size_t)c * 2 + 0) * NCAPS + ii];
        up1[c] = utb[((size_t)c * 2 + 1) * NCAPS + ii];
    }

    float bl[NCLS];
    #pragma unroll
    for (int c = 0; c < NCLS; ++c) {
        float a = 0.f;
        #pragma unroll
        for (int dp = 0; dp < 4; ++dp)
            a = dot2h(((const unsigned*)&up0[c])[dp], vsh[c * 8 + dp], a);
        #pragma unroll
        for (int dp = 0; dp < 4; ++dp)
            a = dot2h(((const unsigned*)&up1[c])[dp], vsh[c * 8 + 4 + dp], a);
        bl[c] = a;
    }

    float m = bl[0];
    #pragma unroll
    for (int c = 1; c < NCLS; ++c) m = fmaxf(m, bl[c]);
    float den = 0.f;
    #pragma unroll
    for (int c = 0; c < NCLS; ++c) den += __expf(bl[c] - m);
    float sid = 1.f / den;
    #pragma unroll
    for (int c = 0; c < NCLS; ++c) bl[c] = __expf(bl[c] - m) * sid;  // bl := w

    #pragma unroll
    for (int c = 0; c < NCLS; ++c) {
        float sacc[KDO];
        #pragma unroll
        for (int dp = 0; dp < 8; ++dp) {
            union { unsigned u; h2_t h; } p;
            p.u = (dp < 4) ? ((const unsigned*)&up0[c])[dp]
                           : ((const unsigned*)&up1[c])[dp - 4];
            sacc[2 * dp]     = bl[c] * (float)p.h.x;
            sacc[2 * dp + 1] = bl[c] * (float)p.h.y;
        }
        float e = bfly16(sacc, lane);
        if ((lane & 3) == 0) red[wave][c * KDO + dm] = e;
    }
    __syncthreads();
    for (int tt = t; tt < NCLS * KDO; tt += CHUNK)
        psOut[((size_t)b * NCH + blockIdx.x) * (NCLS * KDO) + tt]
            = red[0][tt] + red[1][tt];
}

// ---- phase 3 (final only): sum 9 chunk-partials, squash, write out.
__global__ __launch_bounds__(160)
void k_squash(const float* __restrict__ psum, float* __restrict__ out)
{
    const int b = blockIdx.x;
    const int t = threadIdx.x;                         // 0..159
    if (t >= NCLS * KDO) return;

    float s = 0.f;
    #pragma unroll
    for (int ch = 0; ch < NCH; ++ch)
        s += psum[((size_t)b * NCH + ch) * (NCLS * KDO) + t];

    float nsq = s * s;                                 // reduce within c-group
    nsq += __shfl_xor(nsq, 8, 16);
    nsq += __shfl_xor(nsq, 4, 16);
    nsq += __shfl_xor(nsq, 2, 16);
    nsq += __shfl_xor(nsq, 1, 16);
    float sc = sqrtf(nsq) / (1.f + nsq);               // (nsq/(1+nsq))/sqrt(nsq)
    out[(size_t)b * NCLS * KDO + t] = s * sc;
}

// ---- fallback (small ws): round-1 fp32 fused kernel, proven correct ----
__global__ __launch_bounds__(256, 2)
void caps_routing_fb(const float* __restrict__ x, const float* __restrict__ W,
                     float* __restrict__ out)
{
    const int b    = blockIdx.x;
    const int t    = threadIdx.x;
    const int lane = t & 63;
    const int wave = t >> 6;
    __shared__ float v_prev[NCLS * KDO];
    __shared__ float redf[NCLS * 4 * KDO];
    float4 xr[5][2];
    const float4* x4 = reinterpret_cast<const float4*>(x + (size_t)b * NCAPS * 8);
    #pragma unroll
    for (int j = 0; j < 5; ++j) {
        int i = t + 256 * j;
        if (i < NCAPS) { xr[j][0] = x4[2 * i]; xr[j][1] = x4[2 * i + 1]; }
    }
    float blog[5][NCLS];
    #pragma unroll
    for (int j = 0; j < 5; ++j)
        #pragma unroll
        for (int c = 0; c < NCLS; ++c) blog[j][c] = 0.f;
    const float4* W4 = reinterpret_cast<const float4*>(W);
    for (int it = 0; it < 3; ++it) {
        if (it > 0) {
            for (int c = 0; c < NCLS; ++c) {
                float vp[KDO];
                #pragma unroll
                for (int d = 0; d < KDO; ++d) vp[d] = v_prev[c * KDO + d];
                #pragma unroll
                for (int j = 0; j < 5; ++j) {
                    int i = t + 256 * j;
                    if (i < NCAPS) {
                        size_t wbx = (size_t)(c * NCAPS + i) * 32;
                        float a = 0.f;
                        #pragma unroll
                        for (int d = 0; d < KDO; ++d) {
                            float4 w0 = W4[wbx + 2 * d]; float4 w1 = W4[wbx + 2 * d + 1];
                            float u = w0.x*xr[j][0].x + w0.y*xr[j][0].y + w0.z*xr[j][0].z
                                    + w0.w*xr[j][0].w + w1.x*xr[j][1].x + w1.y*xr[j][1].y
                                    + w1.z*xr[j][1].z + w1.w*xr[j][1].w;
                            a += u * vp[d];
                        }
                        blog[j][c] += a;
                    }
                }
            }
        }
        float sm2[5], sid2[5];
        #pragma unroll
        for (int j = 0; j < 5; ++j) {
            int i = t + 256 * j;
            if (i < NCAPS) {
                float m = blog[j][0];
                #pragma unroll
                for (int c = 1; c < NCLS; ++c) m = fmaxf(m, blog[j][c]);
                float den = 0.f;
                #pragma unroll
                for (int c = 0; c < NCLS; ++c) den += __expf(blog[j][c] - m);
                sm2[j] = m; sid2[j] = 1.f / den;
            }
        }
        for (int c = 0; c < NCLS; ++c) {
            float acc[KDO];
            #pragma unroll
            for (int d = 0; d < KDO; ++d) acc[d] = 0.f;
            #pragma unroll
            for (int j = 0; j < 5; ++j) {
                int i = t + 256 * j;
                if (i < NCAPS) {
                    float wq = __expf(blog[j][c] - sm2[j]) * sid2[j];
                    size_t wbx = (size_t)(c * NCAPS + i) * 32;
                    #pragma unroll
                    for (int d = 0; d < KDO; ++d) {
                        float4 w0 = W4[wbx + 2 * d]; float4 w1 = W4[wbx + 2 * d + 1];
                        float u = w0.x*xr[j][0].x + w0.y*xr[j][0].y + w0.z*xr[j][0].z
                                + w0.w*xr[j][0].w + w1.x*xr[j][1].x + w1.y*xr[j][1].y
                                + w1.z*xr[j][1].z + w1.w*xr[j][1].w;
                        acc[d] += wq * u;
                    }
                }
            }
            #pragma unroll
            for (int d = 0; d < KDO; ++d) {
                float v = acc[d];
                v += __shfl_xor(v, 32, 64); v += __shfl_xor(v, 16, 64);
                v += __shfl_xor(v,  8, 64); v += __shfl_xor(v,  4, 64);
                v += __shfl_xor(v,  2, 64); v += __shfl_xor(v,  1, 64);
                if (lane == 0) redf[(c * 4 + wave) * KDO + d] = v;
            }
        }
        __syncthreads();
        if (t < NCLS * KDO) {
            int c = t >> 4, d = t & 15;
            float s = redf[(c*4+0)*KDO+d] + redf[(c*4+1)*KDO+d]
                    + redf[(c*4+2)*KDO+d] + redf[(c*4+3)*KDO+d];
            float nsq = s * s;
            nsq += __shfl_xor(nsq, 8, 16); nsq += __shfl_xor(nsq, 4, 16);
            nsq += __shfl_xor(nsq, 2, 16); nsq += __shfl_xor(nsq, 1, 16);
            float scale = sqrtf(nsq) / (1.f + nsq);
            float vv = s * scale;
            v_prev[t] = vv;
            if (it == 2) out[(size_t)b * NCLS * KDO + t] = vv;
        }
        __syncthreads();
    }
}

extern "C" void kernel_launch(void* const* d_in, const int* in_sizes, int n_in,
                              void* d_out, int out_size, void* d_ws, size_t ws_size,
                              hipStream_t stream) {
    const float* x = (const float*)d_in[0];              // [256, 1152, 8] fp32
    const float4* W4 = (const float4*)d_in[1];           // [10, 1152, 1, 16, 8] fp32
    float* out = (float*)d_out;                          // [256, 10, 1, 16] fp32
    (void)in_sizes; (void)n_in; (void)out_size;

    const size_t WT = (size_t)NCLS * KDO * NCAPS * sizeof(u4);            //  2.95 MB
    const size_t XH = (size_t)NB * NCAPS * sizeof(u4);                    //  4.72 MB
    const size_t UT = (size_t)NB * NCLS * 2 * NCAPS * sizeof(u4);         // 94.37 MB
    const size_t PS = (size_t)NB * NCH * NCLS * KDO * sizeof(float);      //  1.47 MB
    const size_t need = WT + XH + UT + 3 * PS;                            // ~106 MB

    if (ws_size >= need) {
        char* p = (char*)d_ws;
        u4* Wt    = (u4*)p;    p += WT;
        u4* xp    = (u4*)p;    p += XH;
        u4* ut    = (u4*)p;    p += UT;
        float* ps0 = (float*)p; p += PS;
        float* ps1 = (float*)p; p += PS;
        float* ps2 = (float*)p;

        int totalW = NCLS * NCAPS * KDO;
        int totalX = NB * NCAPS;
        pack_W_f16<<<dim3((totalW + 255) / 256), dim3(256), 0, stream>>>(W4, Wt);
        pack_x_f16<<<dim3((totalX + 255) / 256), dim3(256), 0, stream>>>(
            (const float4*)x, xp);
        k_uhat<<<dim3(NCH, NB / BBAT, NCLS / 2), dim3(CHUNK), 0, stream>>>(
            Wt, xp, ut, ps0);
        k_iter<<<dim3(NCH, NB), dim3(CHUNK), 0, stream>>>(ut, ps0, 0.1f, nullptr, ps1);
        k_iter<<<dim3(NCH, NB), dim3(CHUNK), 0, stream>>>(ut, ps0, 0.1f, ps1, ps2);
        k_squash<<<dim3(NB), dim3(160), 0, stream>>>(ps2, out);
    } else {
        caps_routing_fb<<<dim3(NB), dim3(256), 0, stream>>>(x, (const float*)d_in[1], out);
    }
}